// Round 2
// baseline (174.831 us; speedup 1.0000x reference)
//
#include <hip/hip_runtime.h>
#include <hip/hip_bf16.h>
#include <stdint.h>

// Problem constants (fixed by setup_inputs)
#define T_SEQ  2048
#define DMODEL 1024
#define NBATCH 2
#define NHEAD  16
#define DHEAD  64
#define MTOT   (NBATCH * T_SEQ)   // 4096 rows for all projection GEMMs

typedef __attribute__((ext_vector_type(8))) short short8_t;  // 8 bf16 (4 VGPRs) MFMA A/B frag
typedef __attribute__((ext_vector_type(4))) float f32x4;     // MFMA C/D frag

typedef const __attribute__((address_space(1))) void* gas_t;
typedef __attribute__((address_space(3))) void* las_t;

__device__ __forceinline__ ushort f2bf(float f) {
    union { float f; uint32_t u; } cv; cv.f = f;
    uint32_t u = cv.u;
    return (ushort)((u + 0x7FFFu + ((u >> 16) & 1u)) >> 16);  // RNE
}

// ---------------- fp32 -> bf16 convert of q,k,v into one contiguous [3][4096][1024] ----------------
__global__ __launch_bounds__(256) void convert_qkv_kernel(
        const float* __restrict__ q, const float* __restrict__ k,
        const float* __restrict__ v, ushort* __restrict__ outb) {
    const size_t per = (size_t)MTOT * DMODEL / 4;           // float4s per tensor = 1048576
    size_t idx = (size_t)blockIdx.x * 256 + threadIdx.x;
    int t = (int)(idx / per);
    size_t i = idx - (size_t)t * per;
    const float4* src = (const float4*)(t == 0 ? q : (t == 1 ? k : v));
    float4 val = src[i];
    ushort4 o;
    o.x = f2bf(val.x); o.y = f2bf(val.y); o.z = f2bf(val.z); o.w = f2bf(val.w);
    ((ushort4*)outb)[(size_t)t * per + i] = o;
}

// ---------------- W fp32 [K][N] -> bf16 transposed [N][K] (so GEMM B-frags are contiguous) ----------
__global__ __launch_bounds__(256) void convw_kernel(
        const float* __restrict__ Wq, const float* __restrict__ Wk,
        const float* __restrict__ Wv, const float* __restrict__ Wo,
        ushort* __restrict__ wt) {
    __shared__ float tile[32][33];                          // +1 pad: conflict-free transpose
    int z = blockIdx.z;
    const float* W = z == 0 ? Wq : z == 1 ? Wk : z == 2 ? Wv : Wo;
    ushort* out = wt + (size_t)z * DMODEL * DMODEL;
    int tx = threadIdx.x, ty = threadIdx.y;                 // 32 x 8
    int k0 = blockIdx.x * 32, n0 = blockIdx.y * 32;
    #pragma unroll
    for (int i = 0; i < 4; i++)
        tile[ty + i * 8][tx] = W[(size_t)(k0 + ty + i * 8) * DMODEL + n0 + tx];
    __syncthreads();
    #pragma unroll
    for (int i = 0; i < 4; i++)
        out[(size_t)(n0 + ty + i * 8) * DMODEL + k0 + tx] = f2bf(tile[tx][ty + i * 8]);
}

// ---------------- bf16 GEMM, m97 structure: C[M][N] = A[M][K] * Bt[N][K]^T ----------------
// 128x128 tile, BK=32, 4 waves (2x2), 4x4 16x16x32 MFMA accs per wave, global_load_lds(16B) staging.
template <bool OUT_F32>
__global__ __launch_bounds__(256, 2) void gemm_bt_kernel(
        const ushort* __restrict__ Aall, const ushort* __restrict__ Btall,
        void* __restrict__ Call, int M, int N, int K) {
    const ushort* A  = Aall  + (size_t)blockIdx.z * M * K;
    const ushort* Bt = Btall + (size_t)blockIdx.z * N * K;

    __shared__ ushort As[128 * 32];   // [128 rows][32 k] row-major, 8 KB
    __shared__ ushort Bs[128 * 32];

    const int tid  = threadIdx.x;
    const int lane = tid & 63;
    const int wid  = tid >> 6;
    const int wr = wid >> 1, wc = wid & 1;          // 2x2 wave grid, 64x64 out each
    const int m_base = blockIdx.x * 128;
    const int n_base = blockIdx.y * 128;

    f32x4 acc[4][4] = {};

    const int srow = lane >> 2;                     // staging: 16 rows / chunk
    const int scol = (lane & 3) * 8;                // 4 x 16B per row

    for (int kk = 0; kk < K; kk += 32) {
        __syncthreads();                            // prior tile's reads complete
        #pragma unroll
        for (int i = 0; i < 2; i++) {
            int c = wid * 2 + i;                    // 8 x 1KB chunks each for A and B
            const ushort* ga = A  + (size_t)(m_base + c * 16 + srow) * K + kk + scol;
            const ushort* gb = Bt + (size_t)(n_base + c * 16 + srow) * K + kk + scol;
            __builtin_amdgcn_global_load_lds((gas_t)ga, (las_t)(As + c * 512), 16, 0, 0);
            __builtin_amdgcn_global_load_lds((gas_t)gb, (las_t)(Bs + c * 512), 16, 0, 0);
        }
        __syncthreads();                            // drains vmcnt -> staged data visible
        short8_t a[4], b[4];
        #pragma unroll
        for (int mt = 0; mt < 4; mt++)
            a[mt] = *(const short8_t*)(As + (wr * 64 + mt * 16 + (lane & 15)) * 32 + (lane >> 4) * 8);
        #pragma unroll
        for (int nt = 0; nt < 4; nt++)
            b[nt] = *(const short8_t*)(Bs + (wc * 64 + nt * 16 + (lane & 15)) * 32 + (lane >> 4) * 8);
        #pragma unroll
        for (int mt = 0; mt < 4; mt++)
            #pragma unroll
            for (int nt = 0; nt < 4; nt++)
                acc[mt][nt] = __builtin_amdgcn_mfma_f32_16x16x32_bf16(a[mt], b[nt], acc[mt][nt], 0, 0, 0);
    }

    // Epilogue: D layout col = lane&15, row = (lane>>4)*4 + r  [verified m89/m91]
    const int row0 = m_base + wr * 64 + (lane >> 4) * 4;
    const int col0 = n_base + wc * 64 + (lane & 15);
    if constexpr (OUT_F32) {
        float* C = (float*)Call + (size_t)blockIdx.z * M * N;
        #pragma unroll
        for (int mt = 0; mt < 4; mt++)
            #pragma unroll
            for (int nt = 0; nt < 4; nt++)
                #pragma unroll
                for (int r = 0; r < 4; r++)
                    C[(size_t)(row0 + mt * 16 + r) * N + col0 + nt * 16] = acc[mt][nt][r];
    } else {
        ushort* C = (ushort*)Call + (size_t)blockIdx.z * M * N;
        #pragma unroll
        for (int mt = 0; mt < 4; mt++)
            #pragma unroll
            for (int nt = 0; nt < 4; nt++)
                #pragma unroll
                for (int r = 0; r < 4; r++)
                    C[(size_t)(row0 + mt * 16 + r) * N + col0 + nt * 16] = f2bf(acc[mt][nt][r]);
    }
}

// ---------------- causal flash attention ----------------
// grid = (16 q-blocks, 32 b*h). Block: 4 waves, each owns 32 q-rows of the 128-row Q block.
// Swapped QK^T: S^T = mfma(K_frag, Q_frag) so softmax-reduce over kv is shfl_xor(16)+shfl_xor(32).
__global__ __launch_bounds__(256, 2) void attn_kernel(
        const ushort* __restrict__ Qp, const ushort* __restrict__ Kp,
        const ushort* __restrict__ Vp, ushort* __restrict__ Op) {
    __shared__ ushort Ksh[64 * 72];        // K tile  [kv][dk], pad 72 -> aligned (144B = 9x16B rows)
    __shared__ ushort Vts[64 * 72];        // V tile transposed [dv][kv]
    __shared__ ushort Psh[4 * 32 * 72];    // per-wave P [32 q][64 kv] (padded)

    const int tid = threadIdx.x, lane = tid & 63, w = tid >> 6;
    const int qi = 15 - (int)blockIdx.x;   // heavy (late, most KV tiles) blocks first
    const int bh = blockIdx.y;
    const int b = bh >> 4, h = bh & 15;
    const int q0 = qi * 128;

    const ushort* Qb = Qp + (size_t)(b * T_SEQ) * DMODEL + h * DHEAD;
    const ushort* Kb = Kp + (size_t)(b * T_SEQ) * DMODEL + h * DHEAD;
    const ushort* Vb = Vp + (size_t)(b * T_SEQ) * DMODEL + h * DHEAD;

    // Q B-operand frags straight from global (reused across all KV tiles):
    // lane holds Q[q0 + w*32 + qt*16 + (lane&15)][kc*32 + (lane>>4)*8 + e]
    short8_t qf[2][2];
    #pragma unroll
    for (int qt = 0; qt < 2; qt++)
        #pragma unroll
        for (int kc = 0; kc < 2; kc++)
            qf[qt][kc] = *(const short8_t*)(Qb + (size_t)(q0 + w * 32 + qt * 16 + (lane & 15)) * DMODEL
                                            + kc * 32 + (lane >> 4) * 8);

    f32x4 acc_o[2][4] = {};                 // O[q 32][dv 64] per wave
    float mrun[2] = {-1e30f, -1e30f};
    float lrun[2] = {0.f, 0.f};

    const int full   = q0 >> 6;             // tiles below this need no mask
    const int ntiles = full + 2;

    for (int t = 0; t < ntiles; t++) {
        const int kv0 = t * 64;
        __syncthreads();                    // previous tile fully consumed
        {   // stage K [64][64] -> Ksh [64][72]; thread: 32 rows x 8 chunks, 2 row-halves
            int r = tid >> 3, ck = tid & 7;
            #pragma unroll
            for (int i = 0; i < 2; i++) {
                short8_t kvv = *(const short8_t*)(Kb + (size_t)(kv0 + r + i * 32) * DMODEL + ck * 8);
                *(short8_t*)(Ksh + (r + i * 32) * 72 + ck * 8) = kvv;
            }
        }
        {   // stage V transposed: thread: kv pair = tid&31, dv chunk = tid>>5 (conflict-free b32 writes)
            int kvp = tid & 31, dvc = tid >> 5;
            const ushort* vsrc = Vb + (size_t)(kv0 + kvp * 2) * DMODEL + dvc * 8;
            short8_t v0 = *(const short8_t*)(vsrc);
            short8_t v1 = *(const short8_t*)(vsrc + DMODEL);
            #pragma unroll
            for (int d = 0; d < 8; d++) {
                uint32_t pk = (uint32_t)(ushort)v0[d] | ((uint32_t)(ushort)v1[d] << 16);
                *(uint32_t*)(Vts + (dvc * 8 + d) * 72 + kvp * 2) = pk;
            }
        }
        __syncthreads();                    // staging visible

        // S^T = K * Q^T : s[kvT][qt], lane holds S^T[kv=kvT*16+(l>>4)*4+r][q=qt*16+(l&15)]
        f32x4 s[4][2] = {};
        short8_t kf[4][2];
        #pragma unroll
        for (int kvT = 0; kvT < 4; kvT++)
            #pragma unroll
            for (int kc = 0; kc < 2; kc++)
                kf[kvT][kc] = *(const short8_t*)(Ksh + (kvT * 16 + (lane & 15)) * 72
                                                 + kc * 32 + (lane >> 4) * 8);
        #pragma unroll
        for (int kvT = 0; kvT < 4; kvT++)
            #pragma unroll
            for (int qt = 0; qt < 2; qt++)
                #pragma unroll
                for (int kc = 0; kc < 2; kc++)
                    s[kvT][qt] = __builtin_amdgcn_mfma_f32_16x16x32_bf16(kf[kvT][kc], qf[qt][kc], s[kvT][qt], 0, 0, 0);

        // scale + causal mask + tile max
        const float scale = 0.125f;         // 1/sqrt(64)
        const bool need_mask = (t >= full);
        const int qg = q0 + w * 32 + (lane & 15);
        float pmax[2] = {-1e30f, -1e30f};
        #pragma unroll
        for (int qt = 0; qt < 2; qt++)
            #pragma unroll
            for (int kvT = 0; kvT < 4; kvT++)
                #pragma unroll
                for (int r = 0; r < 4; r++) {
                    float val = s[kvT][qt][r] * scale;
                    if (need_mask) {
                        int kv_g = kv0 + kvT * 16 + (lane >> 4) * 4 + r;
                        if (kv_g > qg + qt * 16) val = -1e30f;
                    }
                    s[kvT][qt][r] = val;
                    pmax[qt] = fmaxf(pmax[qt], val);
                }
        #pragma unroll
        for (int qt = 0; qt < 2; qt++) {    // reduce over the 4 kv lane-groups
            float vv = pmax[qt];
            vv = fmaxf(vv, __shfl_xor(vv, 16));
            vv = fmaxf(vv, __shfl_xor(vv, 32));
            pmax[qt] = vv;
        }
        float fac[2];
        #pragma unroll
        for (int qt = 0; qt < 2; qt++) {
            float mnew = fmaxf(mrun[qt], pmax[qt]);
            fac[qt] = __expf(mrun[qt] - mnew);
            mrun[qt] = mnew;
        }
        float psum[2] = {0.f, 0.f};
        #pragma unroll
        for (int qt = 0; qt < 2; qt++)
            #pragma unroll
            for (int kvT = 0; kvT < 4; kvT++)
                #pragma unroll
                for (int r = 0; r < 4; r++) {
                    float p = __expf(s[kvT][qt][r] - mrun[qt]);
                    s[kvT][qt][r] = p;
                    psum[qt] += p;
                }
        #pragma unroll
        for (int qt = 0; qt < 2; qt++) {
            float vv = psum[qt];
            vv += __shfl_xor(vv, 16);
            vv += __shfl_xor(vv, 32);
            lrun[qt] = lrun[qt] * fac[qt] + vv;
        }

        // P (bf16) -> wave-private LDS region, [q][kv] so PV A-frags are contiguous b128 reads
        ushort* Pw = Psh + w * 32 * 72;
        #pragma unroll
        for (int qt = 0; qt < 2; qt++)
            #pragma unroll
            for (int kvT = 0; kvT < 4; kvT++) {
                uint32_t lo = (uint32_t)f2bf(s[kvT][qt][0]) | ((uint32_t)f2bf(s[kvT][qt][1]) << 16);
                uint32_t hi = (uint32_t)f2bf(s[kvT][qt][2]) | ((uint32_t)f2bf(s[kvT][qt][3]) << 16);
                uint2 pk; pk.x = lo; pk.y = hi;
                *(uint2*)(Pw + (qt * 16 + (lane & 15)) * 72 + kvT * 16 + (lane >> 4) * 4) = pk;
            }

        // rescale O accumulators (O layout q = (l>>4)*4+r -> shfl fac from S^T layout lanes 0..15)
        #pragma unroll
        for (int qt = 0; qt < 2; qt++)
            #pragma unroll
            for (int r = 0; r < 4; r++) {
                float f = __shfl(fac[qt], (lane >> 4) * 4 + r);
                #pragma unroll
                for (int dt = 0; dt < 4; dt++) acc_o[qt][dt][r] *= f;
            }

        __syncthreads();                    // cross-lane P visibility (wave-safe ordering)

        // O += P * V
        short8_t vf[4][2], pf[2][2];
        #pragma unroll
        for (int dt = 0; dt < 4; dt++)
            #pragma unroll
            for (int kc = 0; kc < 2; kc++)
                vf[dt][kc] = *(const short8_t*)(Vts + (dt * 16 + (lane & 15)) * 72
                                                + kc * 32 + (lane >> 4) * 8);
        #pragma unroll
        for (int qt = 0; qt < 2; qt++)
            #pragma unroll
            for (int kc = 0; kc < 2; kc++)
                pf[qt][kc] = *(const short8_t*)(Pw + (qt * 16 + (lane & 15)) * 72
                                                + kc * 32 + (lane >> 4) * 8);
        #pragma unroll
        for (int qt = 0; qt < 2; qt++)
            #pragma unroll
            for (int dt = 0; dt < 4; dt++)
                #pragma unroll
                for (int kc = 0; kc < 2; kc++)
                    acc_o[qt][dt] = __builtin_amdgcn_mfma_f32_16x16x32_bf16(pf[qt][kc], vf[dt][kc], acc_o[qt][dt], 0, 0, 0);
    }

    // normalize + store bf16 to Op [B*T][H*64]
    ushort* Ob = Op + (size_t)(b * T_SEQ) * DMODEL + h * DHEAD;
    #pragma unroll
    for (int qt = 0; qt < 2; qt++)
        #pragma unroll
        for (int r = 0; r < 4; r++) {
            float linv = 1.f / __shfl(lrun[qt], (lane >> 4) * 4 + r);
            int qrow = q0 + w * 32 + qt * 16 + (lane >> 4) * 4 + r;
            #pragma unroll
            for (int dt = 0; dt < 4; dt++)
                Ob[(size_t)qrow * DMODEL + dt * 16 + (lane & 15)] = f2bf(acc_o[qt][dt][r] * linv);
        }
}

// ---------------- launch ----------------
extern "C" void kernel_launch(void* const* d_in, const int* in_sizes, int n_in,
                              void* d_out, int out_size, void* d_ws, size_t ws_size,
                              hipStream_t stream) {
    (void)in_sizes; (void)n_in; (void)out_size; (void)ws_size;
    const float* q  = (const float*)d_in[0];
    const float* k  = (const float*)d_in[1];
    const float* v  = (const float*)d_in[2];
    // d_in[3] = mask (causal tril) -- implemented analytically
    const float* Wq = (const float*)d_in[4];
    const float* Wk = (const float*)d_in[5];
    const float* Wv = (const float*)d_in[6];
    const float* Wo = (const float*)d_in[7];

    ushort* ws = (ushort*)d_ws;
    const size_t MK = (size_t)MTOT * DMODEL;    // 4194304 elems
    const size_t NK = (size_t)DMODEL * DMODEL;  // 1048576 elems
    ushort* qkvb = ws;                    // bf16 q,k,v        [3*MK]   (24 MB)
    ushort* wt   = ws + 3 * MK;           // bf16 W^T x4       [4*NK]   ( 8 MB)
    ushort* qkvp = ws + 3 * MK + 4 * NK;  // bf16 Q,K,V proj   [3*MK]   (24 MB)
    ushort* Op   = ws;                    // attn out reuses qkvb region ( 8 MB)
    // total ws footprint: 56 MB

    convert_qkv_kernel<<<dim3(12288), dim3(256), 0, stream>>>(q, k, v, qkvb);
    convw_kernel<<<dim3(32, 32, 4), dim3(32, 8), 0, stream>>>(Wq, Wk, Wv, Wo, wt);
    gemm_bt_kernel<false><<<dim3(32, 8, 3), dim3(256), 0, stream>>>(qkvb, wt, (void*)qkvp,
                                                                    MTOT, DMODEL, DMODEL);
    attn_kernel<<<dim3(16, 32), dim3(256), 0, stream>>>(qkvp, qkvp + MK, qkvp + 2 * MK, Op);
    gemm_bt_kernel<true><<<dim3(32, 8, 1), dim3(256), 0, stream>>>(Op, wt + 3 * NK, d_out,
                                                                   MTOT, DMODEL, DMODEL);
}

// Round 3
// 134.427 us; speedup vs baseline: 1.3006x; 1.3006x over previous
//
#include <hip/hip_runtime.h>
#include <hip/hip_bf16.h>
#include <stdint.h>

// Problem constants (fixed by setup_inputs)
#define T_SEQ  2048
#define DMODEL 1024
#define NBATCH 2
#define NHEAD  16
#define DHEAD  64
#define MTOT   (NBATCH * T_SEQ)   // 4096 rows for all projection GEMMs

typedef __attribute__((ext_vector_type(8))) short short8_t;  // 8 bf16 (4 VGPRs) MFMA A/B frag
typedef __attribute__((ext_vector_type(4))) float f32x4;     // MFMA C/D frag

typedef const __attribute__((address_space(1))) void* gas_t;
typedef __attribute__((address_space(3))) void* las_t;

__device__ __forceinline__ ushort f2bf(float f) {
    union { float f; uint32_t u; } cv; cv.f = f;
    uint32_t u = cv.u;
    return (ushort)((u + 0x7FFFu + ((u >> 16) & 1u)) >> 16);  // RNE
}

// ---------------- fp32 -> bf16 convert of q,k,v into one contiguous [3][4096][1024] ----------------
__global__ __launch_bounds__(256) void convert_qkv_kernel(
        const float* __restrict__ q, const float* __restrict__ k,
        const float* __restrict__ v, ushort* __restrict__ outb) {
    const size_t per = (size_t)MTOT * DMODEL / 4;           // float4s per tensor = 1048576
    size_t idx = (size_t)blockIdx.x * 256 + threadIdx.x;
    int t = (int)(idx / per);
    size_t i = idx - (size_t)t * per;
    const float4* src = (const float4*)(t == 0 ? q : (t == 1 ? k : v));
    float4 val = src[i];
    ushort4 o;
    o.x = f2bf(val.x); o.y = f2bf(val.y); o.z = f2bf(val.z); o.w = f2bf(val.w);
    ((ushort4*)outb)[(size_t)t * per + i] = o;
}

// ---------------- W fp32 [K][N] -> bf16 transposed [N][K]; Wq gets 1/sqrt(dk) folded in ------------
__global__ __launch_bounds__(256) void convw_kernel(
        const float* __restrict__ Wq, const float* __restrict__ Wk,
        const float* __restrict__ Wv, const float* __restrict__ Wo,
        ushort* __restrict__ wt) {
    __shared__ float tile[32][33];                          // +1 pad: conflict-free transpose
    int z = blockIdx.z;
    const float* W = z == 0 ? Wq : z == 1 ? Wk : z == 2 ? Wv : Wo;
    const float sc = (z == 0) ? 0.125f : 1.0f;              // 1/sqrt(64) folded into Wq
    ushort* out = wt + (size_t)z * DMODEL * DMODEL;
    int tx = threadIdx.x, ty = threadIdx.y;                 // 32 x 8
    int k0 = blockIdx.x * 32, n0 = blockIdx.y * 32;
    #pragma unroll
    for (int i = 0; i < 4; i++)
        tile[ty + i * 8][tx] = W[(size_t)(k0 + ty + i * 8) * DMODEL + n0 + tx];
    __syncthreads();
    #pragma unroll
    for (int i = 0; i < 4; i++)
        out[(size_t)(n0 + ty + i * 8) * DMODEL + k0 + tx] = f2bf(tile[tx][ty + i * 8] * sc);
}

// ---------------- bf16 GEMM, m97 structure: C[M][N] = A[M][K] * Bt[N][K]^T ----------------
// 128x128 tile, BK=32, 4 waves (2x2), 4x4 16x16x32 MFMA accs per wave, global_load_lds(16B) staging.
template <bool OUT_F32>
__global__ __launch_bounds__(256, 2) void gemm_bt_kernel(
        const ushort* __restrict__ Aall, const ushort* __restrict__ Btall,
        void* __restrict__ Call, int M, int N, int K) {
    const ushort* A  = Aall  + (size_t)blockIdx.z * M * K;
    const ushort* Bt = Btall + (size_t)blockIdx.z * N * K;

    __shared__ ushort As[128 * 32];   // [128 rows][32 k] row-major, 8 KB
    __shared__ ushort Bs[128 * 32];

    const int tid  = threadIdx.x;
    const int lane = tid & 63;
    const int wid  = tid >> 6;
    const int wr = wid >> 1, wc = wid & 1;          // 2x2 wave grid, 64x64 out each
    const int m_base = blockIdx.x * 128;
    const int n_base = blockIdx.y * 128;

    f32x4 acc[4][4] = {};

    const int srow = lane >> 2;                     // staging: 16 rows / chunk
    const int scol = (lane & 3) * 8;                // 4 x 16B per row

    for (int kk = 0; kk < K; kk += 32) {
        __syncthreads();                            // prior tile's reads complete
        #pragma unroll
        for (int i = 0; i < 2; i++) {
            int c = wid * 2 + i;                    // 8 x 1KB chunks each for A and B
            const ushort* ga = A  + (size_t)(m_base + c * 16 + srow) * K + kk + scol;
            const ushort* gb = Bt + (size_t)(n_base + c * 16 + srow) * K + kk + scol;
            __builtin_amdgcn_global_load_lds((gas_t)ga, (las_t)(As + c * 512), 16, 0, 0);
            __builtin_amdgcn_global_load_lds((gas_t)gb, (las_t)(Bs + c * 512), 16, 0, 0);
        }
        __syncthreads();                            // drains vmcnt -> staged data visible
        short8_t a[4], b[4];
        #pragma unroll
        for (int mt = 0; mt < 4; mt++)
            a[mt] = *(const short8_t*)(As + (wr * 64 + mt * 16 + (lane & 15)) * 32 + (lane >> 4) * 8);
        #pragma unroll
        for (int nt = 0; nt < 4; nt++)
            b[nt] = *(const short8_t*)(Bs + (wc * 64 + nt * 16 + (lane & 15)) * 32 + (lane >> 4) * 8);
        #pragma unroll
        for (int mt = 0; mt < 4; mt++)
            #pragma unroll
            for (int nt = 0; nt < 4; nt++)
                acc[mt][nt] = __builtin_amdgcn_mfma_f32_16x16x32_bf16(a[mt], b[nt], acc[mt][nt], 0, 0, 0);
    }

    // Epilogue: D layout col = lane&15, row = (lane>>4)*4 + r  [verified m89/m91]
    const int row0 = m_base + wr * 64 + (lane >> 4) * 4;
    const int col0 = n_base + wc * 64 + (lane & 15);
    if constexpr (OUT_F32) {
        float* C = (float*)Call + (size_t)blockIdx.z * M * N;
        #pragma unroll
        for (int mt = 0; mt < 4; mt++)
            #pragma unroll
            for (int nt = 0; nt < 4; nt++)
                #pragma unroll
                for (int r = 0; r < 4; r++)
                    C[(size_t)(row0 + mt * 16 + r) * N + col0 + nt * 16] = acc[mt][nt][r];
    } else {
        ushort* C = (ushort*)Call + (size_t)blockIdx.z * M * N;
        #pragma unroll
        for (int mt = 0; mt < 4; mt++)
            #pragma unroll
            for (int nt = 0; nt < 4; nt++)
                #pragma unroll
                for (int r = 0; r < 4; r++)
                    C[(size_t)(row0 + mt * 16 + r) * N + col0 + nt * 16] = f2bf(acc[mt][nt][r]);
    }
}

// ---------------- causal flash attention, balanced pairs ----------------
// grid = (16 pairs, 32 b*h). Block processes q-blocks qa=blockIdx.x and 31-qa (QBLK=64):
// exactly 33 KV-tiles per block -> perfect static balance. 4 waves, 16 q-rows each.
// T14 async staging: global->reg loads for tile t+1 issued during compute of tile t.
// Swapped QK^T (S^T = mfma(K,Q)), online softmax, P via wave-private LDS (no barrier).
__global__ __launch_bounds__(256, 2) void attn_kernel(
        const ushort* __restrict__ Qp, const ushort* __restrict__ Kp,
        const ushort* __restrict__ Vp, ushort* __restrict__ Op) {
    __shared__ ushort Ksh[64 * 72];        // K tile  [kv][dk], pad 72 (144B rows, 16B-aligned)
    __shared__ ushort Vts[64 * 72];        // V tile transposed [dv][kv]
    __shared__ ushort Psh[4 * 16 * 72];    // per-wave P [16 q][64 kv] (padded)

    const int tid = threadIdx.x, lane = tid & 63, w = tid >> 6;
    const int g = lane >> 4;               // 4 lane-groups of 16
    const int m = lane & 15;
    const int bh = blockIdx.y;
    const int b = bh >> 4, h = bh & 15;

    const ushort* Qb = Qp + (size_t)(b * T_SEQ) * DMODEL + h * DHEAD;
    const ushort* Kb = Kp + (size_t)(b * T_SEQ) * DMODEL + h * DHEAD;
    const ushort* Vb = Vp + (size_t)(b * T_SEQ) * DMODEL + h * DHEAD;
    ushort* Ob = Op + (size_t)(b * T_SEQ) * DMODEL + h * DHEAD;

    const int qa = blockIdx.x;             // first (light) q-block
    const int na = qa + 1;                 // tiles for half A; half B: 31-qa -> 32-qa tiles

    // staging decomposition (per thread)
    const int kr  = tid >> 3, kck = (tid & 7) * 8;   // K: rows kr, kr+32; 16B col chunk
    const int kvp = tid & 31, dvc = tid >> 5;        // V: kv pair, dv 8-chunk

    short8_t kreg0, kreg1, vreg0, vreg1;             // prefetched K/V tile
    auto LOADKV = [&](int kv0) {
        kreg0 = *(const short8_t*)(Kb + (size_t)(kv0 + kr) * DMODEL + kck);
        kreg1 = *(const short8_t*)(Kb + (size_t)(kv0 + kr + 32) * DMODEL + kck);
        const ushort* vsrc = Vb + (size_t)(kv0 + kvp * 2) * DMODEL + dvc * 8;
        vreg0 = *(const short8_t*)(vsrc);
        vreg1 = *(const short8_t*)(vsrc + DMODEL);
    };

    int qi = qa, q0 = qa * 64;
    short8_t qf[2];
    #pragma unroll
    for (int kc = 0; kc < 2; kc++)
        qf[kc] = *(const short8_t*)(Qb + (size_t)(q0 + w * 16 + m) * DMODEL + kc * 32 + g * 8);

    f32x4 acc_o[4] = {};                   // O[q 16][dv 64] per wave
    float mrun = -1e30f, lrun = 0.f;

    ushort* Pw = Psh + w * 16 * 72;        // wave-private P region

    auto WRITE_O = [&]() {
        #pragma unroll
        for (int r = 0; r < 4; r++) {
            float linv = 1.f / __shfl(lrun, g * 4 + r);
            int qrow = q0 + w * 16 + g * 4 + r;
            #pragma unroll
            for (int dt = 0; dt < 4; dt++)
                Ob[(size_t)qrow * DMODEL + dt * 16 + m] = f2bf(acc_o[dt][r] * linv);
        }
    };

    LOADKV(0);                             // prologue: tile 0 of half A

    for (int tt = 0; tt < 33; ++tt) {
        if (tt == na) {                    // half boundary: finish A, start B
            WRITE_O();
            #pragma unroll
            for (int dt = 0; dt < 4; dt++) acc_o[dt] = f32x4{0.f, 0.f, 0.f, 0.f};
            mrun = -1e30f; lrun = 0.f;
            qi = 31 - qa; q0 = qi * 64;
            #pragma unroll
            for (int kc = 0; kc < 2; kc++)
                qf[kc] = *(const short8_t*)(Qb + (size_t)(q0 + w * 16 + m) * DMODEL + kc * 32 + g * 8);
        }
        const int t = (tt < na) ? tt : tt - na;
        const int kv0 = t * 64;
        const bool need_mask = (t == qi);  // only the diagonal tile is masked

        __syncthreads();                   // previous tile's LDS reads complete
        // stage K from regs
        *(short8_t*)(Ksh + kr * 72 + kck) = kreg0;
        *(short8_t*)(Ksh + (kr + 32) * 72 + kck) = kreg1;
        // stage V transposed (packed b32 writes, conflict-free)
        #pragma unroll
        for (int d = 0; d < 8; d++) {
            uint32_t pk = (uint32_t)(ushort)vreg0[d] | ((uint32_t)(ushort)vreg1[d] << 16);
            *(uint32_t*)(Vts + (dvc * 8 + d) * 72 + kvp * 2) = pk;
        }
        __syncthreads();                   // staged tile visible

        if (tt < 32) {                     // issue next tile's loads: latency hides under compute
            int tn = tt + 1;
            LOADKV(((tn < na) ? tn : tn - na) * 64);
        }

        // S^T = K * Q^T : lane holds S^T[kv = kvT*16 + g*4 + r][q = m]
        f32x4 s[4] = {};
        #pragma unroll
        for (int kvT = 0; kvT < 4; kvT++)
            #pragma unroll
            for (int kc = 0; kc < 2; kc++) {
                short8_t kf = *(const short8_t*)(Ksh + (kvT * 16 + m) * 72 + kc * 32 + g * 8);
                s[kvT] = __builtin_amdgcn_mfma_f32_16x16x32_bf16(kf, qf[kc], s[kvT], 0, 0, 0);
            }

        // causal mask (diagonal tile only) + tile max
        const int qg = q0 + w * 16 + m;
        float pmax = -1e30f;
        #pragma unroll
        for (int kvT = 0; kvT < 4; kvT++)
            #pragma unroll
            for (int r = 0; r < 4; r++) {
                float val = s[kvT][r];
                if (need_mask) {
                    int kv_g = kv0 + kvT * 16 + g * 4 + r;
                    if (kv_g > qg) val = -1e30f;
                }
                s[kvT][r] = val;
                pmax = fmaxf(pmax, val);
            }
        pmax = fmaxf(pmax, __shfl_xor(pmax, 16));
        pmax = fmaxf(pmax, __shfl_xor(pmax, 32));
        float mnew = fmaxf(mrun, pmax);
        float fac = __expf(mrun - mnew);
        mrun = mnew;
        float psum = 0.f;
        #pragma unroll
        for (int kvT = 0; kvT < 4; kvT++)
            #pragma unroll
            for (int r = 0; r < 4; r++) {
                float p = __expf(s[kvT][r] - mrun);
                s[kvT][r] = p;
                psum += p;
            }
        psum += __shfl_xor(psum, 16);
        psum += __shfl_xor(psum, 32);
        lrun = lrun * fac + psum;

        // P (bf16) -> wave-private LDS (same-wave write->read: lgkmcnt-ordered, no barrier)
        #pragma unroll
        for (int kvT = 0; kvT < 4; kvT++) {
            uint32_t lo = (uint32_t)f2bf(s[kvT][0]) | ((uint32_t)f2bf(s[kvT][1]) << 16);
            uint32_t hi = (uint32_t)f2bf(s[kvT][2]) | ((uint32_t)f2bf(s[kvT][3]) << 16);
            uint2 pk; pk.x = lo; pk.y = hi;
            *(uint2*)(Pw + m * 72 + kvT * 16 + g * 4) = pk;
        }

        // rescale O accumulators (O row q = g*4+r; fac valid per q=m on lanes 0..15)
        #pragma unroll
        for (int r = 0; r < 4; r++) {
            float f = __shfl(fac, g * 4 + r);
            #pragma unroll
            for (int dt = 0; dt < 4; dt++) acc_o[dt][r] *= f;
        }

        // O += P * V
        short8_t pf[2];
        #pragma unroll
        for (int kc = 0; kc < 2; kc++)
            pf[kc] = *(const short8_t*)(Pw + m * 72 + kc * 32 + g * 8);
        #pragma unroll
        for (int dt = 0; dt < 4; dt++)
            #pragma unroll
            for (int kc = 0; kc < 2; kc++) {
                short8_t vf = *(const short8_t*)(Vts + (dt * 16 + m) * 72 + kc * 32 + g * 8);
                acc_o[dt] = __builtin_amdgcn_mfma_f32_16x16x32_bf16(pf[kc], vf, acc_o[dt], 0, 0, 0);
            }
    }
    WRITE_O();
}

// ---------------- launch ----------------
extern "C" void kernel_launch(void* const* d_in, const int* in_sizes, int n_in,
                              void* d_out, int out_size, void* d_ws, size_t ws_size,
                              hipStream_t stream) {
    (void)in_sizes; (void)n_in; (void)out_size; (void)ws_size;
    const float* q  = (const float*)d_in[0];
    const float* k  = (const float*)d_in[1];
    const float* v  = (const float*)d_in[2];
    // d_in[3] = mask (causal tril) -- implemented analytically
    const float* Wq = (const float*)d_in[4];
    const float* Wk = (const float*)d_in[5];
    const float* Wv = (const float*)d_in[6];
    const float* Wo = (const float*)d_in[7];

    ushort* ws = (ushort*)d_ws;
    const size_t MK = (size_t)MTOT * DMODEL;    // 4194304 elems
    const size_t NK = (size_t)DMODEL * DMODEL;  // 1048576 elems
    ushort* qkvb = ws;                    // bf16 q,k,v        [3*MK]   (24 MB)
    ushort* wt   = ws + 3 * MK;           // bf16 W^T x4       [4*NK]   ( 8 MB)
    ushort* qkvp = ws + 3 * MK + 4 * NK;  // bf16 Q,K,V proj   [3*MK]   (24 MB)
    ushort* Op   = ws;                    // attn out reuses qkvb region ( 8 MB)
    // total ws footprint: 56 MB

    convert_qkv_kernel<<<dim3(12288), dim3(256), 0, stream>>>(q, k, v, qkvb);
    convw_kernel<<<dim3(32, 32, 4), dim3(32, 8), 0, stream>>>(Wq, Wk, Wv, Wo, wt);
    gemm_bt_kernel<false><<<dim3(32, 8, 3), dim3(256), 0, stream>>>(qkvb, wt, (void*)qkvp,
                                                                    MTOT, DMODEL, DMODEL);
    attn_kernel<<<dim3(16, 32), dim3(256), 0, stream>>>(qkvp, qkvp + MK, qkvp + 2 * MK, Op);
    gemm_bt_kernel<true><<<dim3(32, 8, 1), dim3(256), 0, stream>>>(Op, wt + 3 * NK, d_out,
                                                                   MTOT, DMODEL, DMODEL);
}